// Round 2
// 472.917 us; speedup vs baseline: 1.0128x; 1.0128x over previous
//
#include <hip/hip_runtime.h>
#include <hip/hip_bf16.h>
#include <math.h>

// Problem constants (fixed by setup_inputs)
#define B   8
#define C   512
#define H   128
#define W   128
#define HW  16384          // H*W
#define HWQ 4096           // HW/4 (float4 quads per image plane)
#define BHW 131072         // B*HW
#define NCHUNK 8           // channel chunks
#define CPC    64          // channels per chunk

// native clang vector for nontemporal builtins (HIP_vector_type is rejected)
typedef float  nfloat4 __attribute__((ext_vector_type(4)));

// ---------------------------------------------------------------------------
// Kernel 1: channel-dot partials. grid = NCHUNK * (BHW/4) threads.
// Each thread: one float4 spatial quad, 64 channels -> partial sum.
// Channel split so grid = 1024 blocks (occupancy), no atomics (ws poisoned).
// NOTE: input loads are NORMAL (allocate into L3). Input is exactly 256 MiB
// = Infinity Cache capacity, so after this pass the whole input is resident;
// apply_kernel exploits that.
// ---------------------------------------------------------------------------
__global__ __launch_bounds__(256)
void conv_partial_kernel(const float* __restrict__ in,
                         const float* __restrict__ wv,
                         float* __restrict__ partial) {
    int t = blockIdx.x * 256 + threadIdx.x;      // 0 .. 262143
    int chunk = t >> 15;                         // 0..7
    int quad  = t & 32767;                       // spatial quad over B*HW/4
    int b = quad >> 12;                          // quad / HWQ
    int q = quad & (HWQ - 1);

    const float4* inp = (const float4*)in
        + (size_t)b * (C * HWQ)
        + (size_t)chunk * CPC * HWQ
        + q;
    const float* wc = wv + chunk * CPC;

    float4 acc = make_float4(0.f, 0.f, 0.f, 0.f);
#pragma unroll 8
    for (int c = 0; c < CPC; ++c) {
        float4 v = inp[(size_t)c * HWQ];
        float wcc = wc[c];
        acc.x += v.x * wcc;
        acc.y += v.y * wcc;
        acc.z += v.z * wcc;
        acc.w += v.w * wcc;
    }
    ((float4*)partial)[(size_t)chunk * 32768 + quad] = acc;
}

// ---------------------------------------------------------------------------
// Kernel 2: reduce 8 partials -> x_proj [B*HW], float4-vectorized.
// ---------------------------------------------------------------------------
__global__ __launch_bounds__(256)
void reduce_partial_kernel(const float4* __restrict__ partial,
                           float4* __restrict__ xproj) {
    int t = blockIdx.x * 256 + threadIdx.x;      // 0 .. BHW/4-1
    float4 s = make_float4(0.f, 0.f, 0.f, 0.f);
#pragma unroll
    for (int ch = 0; ch < NCHUNK; ++ch) {
        float4 p = partial[(size_t)ch * (BHW / 4) + t];
        s.x += p.x;
        s.y += p.y;
        s.z += p.z;
        s.w += p.w;
    }
    xproj[t] = s;
}

// ---------------------------------------------------------------------------
// Kernel 3: per-(b,mask) softmax stats over its 64x64 wrapped window.
// 128 blocks x 256 threads; coef[b*16+k] = exp(-max)/Z.
// ---------------------------------------------------------------------------
__global__ __launch_bounds__(256)
void stats_kernel(const float* __restrict__ xproj,
                  float* __restrict__ coef) {
    int bk = blockIdx.x;             // 0..127
    int b = bk >> 4, k = bk & 15;
    int i = k >> 2, j = k & 3;
    int h0 = (16 * i + ((j >> 1) ? 64 : 0)) & (H - 1);
    int w0 = (16 * i + ((j & 1) ? 64 : 0)) & (W - 1);
    const float* x = xproj + b * HW;

    int tid = threadIdx.x;
    float v[16];
    float m = -1e30f;
#pragma unroll
    for (int it = 0; it < 16; ++it) {
        int p = tid + 256 * it;          // 0..4095 window pixel
        int r = p >> 6, c = p & 63;
        int h = (h0 + r) & (H - 1);
        int w = (w0 + c) & (W - 1);
        v[it] = x[h * W + w];
        m = fmaxf(m, v[it]);
    }
    // wave reduce max (wave64)
    for (int off = 32; off > 0; off >>= 1)
        m = fmaxf(m, __shfl_down(m, off, 64));
    __shared__ float sm[4];
    __shared__ float ss[4];
    int lane = tid & 63, wv = tid >> 6;
    if (lane == 0) sm[wv] = m;
    __syncthreads();
    m = fmaxf(fmaxf(sm[0], sm[1]), fmaxf(sm[2], sm[3]));

    float s = 0.f;
#pragma unroll
    for (int it = 0; it < 16; ++it)
        s += expf(v[it] - m);
    for (int off = 32; off > 0; off >>= 1)
        s += __shfl_down(s, off, 64);
    if (lane == 0) ss[wv] = s;
    __syncthreads();
    if (tid == 0) {
        float Z = ss[0] + ss[1] + ss[2] + ss[3];
        coef[bk] = expf(-m) / Z;
    }
}

// ---------------------------------------------------------------------------
// Kernel 4: scale[b,hw] = 1 + exp(x) * sum_{i=0..3} coef[b, 4i+idx(i,h,w)]
// ---------------------------------------------------------------------------
__global__ __launch_bounds__(256)
void scale_kernel(const float* __restrict__ xproj,
                  const float* __restrict__ coef,
                  float* __restrict__ scale) {
    int t = blockIdx.x * 256 + threadIdx.x;      // 0..BHW-1
    int b = t >> 14;
    int hw = t & (HW - 1);
    int h = hw >> 7, w = hw & (W - 1);
    const float* cf = coef + b * 16;
    float acc = 0.f;
#pragma unroll
    for (int i = 0; i < 4; ++i) {
        int hr = (h - 16 * i) & (H - 1);
        int wr = (w - 16 * i) & (W - 1);
        int idx = 4 * i + ((hr < 64) ? 0 : 2) + ((wr < 64) ? 0 : 1);
        acc += cf[idx];
    }
    scale[t] = 1.0f + expf(xproj[t]) * acc;
}

// ---------------------------------------------------------------------------
// Kernel 5: out = in * scale (scale broadcast over 512 channels), float4.
// L3-reuse pass: input (256 MiB) is L3-resident after conv_partial.
//  - REVERSE block order: read conv's most-recently-touched lines first
//    (decreasing-recency order is optimal under LRU pressure).
//  - NON-TEMPORAL output stores: output (256 MiB) must not allocate into
//    L3, or it evicts the resident input while we still need it.
// ---------------------------------------------------------------------------
__global__ __launch_bounds__(256)
void apply_kernel(const float4* __restrict__ in,
                  const float4* __restrict__ scale,
                  float4* __restrict__ out) {
    size_t base = (size_t)(gridDim.x - 1 - blockIdx.x) * 256;
    size_t t = base + threadIdx.x;           // 0..16777215 quads (reversed by block)
    float4 v = in[t];
    int b = (int)(t >> 21);                  // quads per batch = C*HW/4 = 2^21
    int q = (int)(t & (HWQ - 1));            // spatial quad
    float4 s = scale[((size_t)b << 12) + q];
    nfloat4 r;
    r.x = v.x * s.x;
    r.y = v.y * s.y;
    r.z = v.z * s.z;
    r.w = v.w * s.w;
    __builtin_nontemporal_store(r, (nfloat4*)&out[t]);
}

extern "C" void kernel_launch(void* const* d_in, const int* in_sizes, int n_in,
                              void* d_out, int out_size, void* d_ws, size_t ws_size,
                              hipStream_t stream) {
    const float* input  = (const float*)d_in[0];   // [8,512,128,128]
    const float* w_conv = (const float*)d_in[1];   // [512]
    float* out = (float*)d_out;                    // [8,512,128,128]

    // workspace layout (floats): partial[8*131072] | xproj[131072] | coef[128] | scale[131072]
    float* ws      = (float*)d_ws;
    float* partial = ws;                               // 1,048,576 floats
    float* xproj   = ws + (size_t)NCHUNK * BHW;        // +131072
    float* coef    = xproj + BHW;                      // +128
    float* scale   = coef + 128;                       // +131072  (16B-aligned)

    conv_partial_kernel<<<1024, 256, 0, stream>>>(input, w_conv, partial);
    reduce_partial_kernel<<<BHW / 1024, 256, 0, stream>>>(
        (const float4*)partial, (float4*)xproj);
    stats_kernel<<<B * 16, 256, 0, stream>>>(xproj, coef);
    scale_kernel<<<BHW / 256, 256, 0, stream>>>(xproj, coef, scale);
    apply_kernel<<<(B * C * HW / 4) / 256, 256, 0, stream>>>(
        (const float4*)input, (const float4*)scale, (float4*)out);
}